// Round 1
// baseline (942.310 us; speedup 1.0000x reference)
//
#include <hip/hip_runtime.h>

// GAT layer, N=8192, D=256, fused flash-style attention.
// Split-bf16 (hi+lo) MFMA for the logit chain (h, g, QK^T); plain bf16 for PV
// and the output GEMM. All matmuls on matrix cores (16x16x32 bf16 MFMA).

typedef __attribute__((ext_vector_type(8))) short bf16x8;
typedef __attribute__((ext_vector_type(4))) float f32x4;

#define NN 8192
#define DD 256

__device__ __forceinline__ short f2bf(float f) {
  union { float f; unsigned u; } v; v.f = f;
  unsigned r = v.u + 0x7fffu + ((v.u >> 16) & 1u);  // RNE
  return (short)(r >> 16);
}
__device__ __forceinline__ float bf2f(short b) {
  union { unsigned u; float f; } v; v.u = ((unsigned)(unsigned short)b) << 16;
  return v.f;
}

// f32 -> (hi, lo) bf16 split, elementwise
__global__ __launch_bounds__(256) void cvt_split_kernel(const float* __restrict__ in,
                                                        short* __restrict__ hi,
                                                        short* __restrict__ lo, int n) {
  for (int i = blockIdx.x * blockDim.x + threadIdx.x; i < n; i += gridDim.x * blockDim.x) {
    float f = in[i];
    short h = f2bf(f);
    hi[i] = h;
    lo[i] = f2bf(f - bf2f(h));
  }
}

// featT[c][i] = bf16(feat[i][c])   (PV B-operand wants K-major = feat^T)
__global__ __launch_bounds__(256) void featT_kernel(const float* __restrict__ feat,
                                                    short* __restrict__ fT) {
  int c = blockIdx.y;
  int i = blockIdx.x * 256 + threadIdx.x;
  fT[c * NN + i] = f2bf(feat[i * DD + c]);
}

// 256x256 f32 -> transposed bf16 (optionally split hi/lo)
__global__ __launch_bounds__(256) void transpose_split_kernel(const float* __restrict__ in,
                                                              short* __restrict__ tHi,
                                                              short* __restrict__ tLo) {
  int r = blockIdx.x, c = threadIdx.x;
  float f = in[r * DD + c];
  short h = f2bf(f);
  tHi[c * DD + r] = h;
  if (tLo) tLo[c * DD + r] = f2bf(f - bf2f(h));
}

// C[64x64 tile] = A @ BT^T over K=256.  Optional split (Alo/BTlo 3-term),
// optional second plain product (A2@BT2) accumulated, optional ELU epilogue.
// Outputs: f32 and/or bf16 hi(+lo).  Grid (M/64, 256/64), block 256 (4 waves,
// each wave = 16 rows x 64 cols).
__global__ __launch_bounds__(256) void gemm_bt64_kernel(
    const short* __restrict__ Ahi, const short* __restrict__ Alo,
    const short* __restrict__ BThi, const short* __restrict__ BTlo,
    const short* __restrict__ A2, const short* __restrict__ BT2,
    short* __restrict__ outHi, short* __restrict__ outLo,
    float* __restrict__ outF, int doElu) {
  const int lane = threadIdx.x & 63;
  const int w = threadIdx.x >> 6;
  const int l15 = lane & 15;
  const int koff = (lane >> 4) * 8;
  const int row0 = blockIdx.x * 64 + w * 16;
  const int col0 = blockIdx.y * 64;
  f32x4 acc[4] = {};
  const int aoff = (row0 + l15) * DD + koff;
#pragma unroll
  for (int kk = 0; kk < 8; ++kk) {
    bf16x8 ah = *(const bf16x8*)(Ahi + aoff + kk * 32);
#pragma unroll
    for (int cf = 0; cf < 4; ++cf) {
      int boff = (col0 + cf * 16 + l15) * DD + kk * 32 + koff;
      bf16x8 bh = *(const bf16x8*)(BThi + boff);
      acc[cf] = __builtin_amdgcn_mfma_f32_16x16x32_bf16(ah, bh, acc[cf], 0, 0, 0);
      if (Alo) {
        bf16x8 al = *(const bf16x8*)(Alo + aoff + kk * 32);
        acc[cf] = __builtin_amdgcn_mfma_f32_16x16x32_bf16(al, bh, acc[cf], 0, 0, 0);
      }
      if (BTlo) {
        bf16x8 bl = *(const bf16x8*)(BTlo + boff);
        acc[cf] = __builtin_amdgcn_mfma_f32_16x16x32_bf16(ah, bl, acc[cf], 0, 0, 0);
      }
    }
  }
  if (A2) {
#pragma unroll
    for (int kk = 0; kk < 8; ++kk) {
      bf16x8 ah = *(const bf16x8*)(A2 + aoff + kk * 32);
#pragma unroll
      for (int cf = 0; cf < 4; ++cf) {
        bf16x8 bh = *(const bf16x8*)(BT2 + (col0 + cf * 16 + l15) * DD + kk * 32 + koff);
        acc[cf] = __builtin_amdgcn_mfma_f32_16x16x32_bf16(ah, bh, acc[cf], 0, 0, 0);
      }
    }
  }
  const int crow = row0 + (lane >> 4) * 4;
#pragma unroll
  for (int cf = 0; cf < 4; ++cf) {
    int col = col0 + cf * 16 + l15;
#pragma unroll
    for (int r = 0; r < 4; ++r) {
      float v = acc[cf][r];
      if (doElu) v = (v > 0.f) ? v : expm1f(v);
      if (outF) outF[(crow + r) * DD + col] = v;
      if (outHi) {
        short hb = f2bf(v);
        outHi[(crow + r) * DD + col] = hb;
        if (outLo) outLo[(crow + r) * DD + col] = f2bf(v - bf2f(hb));
      }
    }
  }
}

// ax[i] = h[i,:]·a1, ay[i] = h[i,:]·a2  (h reconstructed from hi+lo, f32 math)
__global__ __launch_bounds__(256) void axay_kernel(const short* __restrict__ hHi,
                                                   const short* __restrict__ hLo,
                                                   const float* __restrict__ a1,
                                                   const float* __restrict__ a2,
                                                   float* __restrict__ ax,
                                                   float* __restrict__ ay) {
  const int lane = threadIdx.x & 63;
  const int w = threadIdx.x >> 6;
  const int row = blockIdx.x * 4 + w;
  float s1 = 0.f, s2 = 0.f;
#pragma unroll
  for (int j = 0; j < 4; ++j) {
    int k = lane * 4 + j;
    float hv = bf2f(hHi[row * DD + k]) + bf2f(hLo[row * DD + k]);
    s1 += hv * a1[k];
    s2 += hv * a2[k];
  }
#pragma unroll
  for (int m = 1; m < 64; m <<= 1) {
    s1 += __shfl_xor(s1, m);
    s2 += __shfl_xor(s2, m);
  }
  if (lane == 0) { ax[row] = s1; ay[row] = s2; }
}

// Fused flash attention over the graph.
// Block = 32 rows, 256 threads (4 waves: wr=w>>1 picks 16-row half, wc=w&1
// picks column half).  Per 64-col tile: S = g·h^T (split-bf16 3-term MFMA)
// + ax[j] + ay[i], leaky-relu, adjacency mask, online softmax (LDS S tile),
// then PV accumulate (P bf16 in LDS x featT global).
__global__ __launch_bounds__(256) void attn_kernel(
    const short* __restrict__ gHi, const short* __restrict__ gLo,
    const short* __restrict__ hHi, const short* __restrict__ hLo,
    const short* __restrict__ fT, const float* __restrict__ ax,
    const float* __restrict__ ay, const int* __restrict__ adj,
    short* __restrict__ hp) {
  __shared__ float sS[32][65];   // padded: conflict-free row access
  __shared__ short sP[32][72];   // padded: 16B-aligned rows, spread banks
  __shared__ float sScale[32];
  __shared__ float sL[32];

  const int tid = threadIdx.x;
  const int lane = tid & 63;
  const int w = tid >> 6;
  const int wr = w >> 1, wc = w & 1;
  const int row0 = blockIdx.x * 32;
  const int l15 = lane & 15;
  const int koff = (lane >> 4) * 8;
  const int srow = wr * 16 + (lane >> 4) * 4;  // MFMA C-layout local row base

  // Q-hoist: g fragments (hi+lo) for this wave's 16 rows, all K=256
  bf16x8 ghi[8], glo[8];
  {
    int go = (row0 + wr * 16 + l15) * DD + koff;
#pragma unroll
    for (int kk = 0; kk < 8; ++kk) {
      ghi[kk] = *(const bf16x8*)(gHi + go + kk * 32);
      glo[kk] = *(const bf16x8*)(gLo + go + kk * 32);
    }
  }
  float ay4[4];
#pragma unroll
  for (int r = 0; r < 4; ++r) ay4[r] = ay[row0 + srow + r];

  // softmax thread mapping: 8 lanes per row
  const int smrow = tid >> 3;
  const int smc0 = (tid & 7) * 8;
  float m_run = -__builtin_inff();
  float l_run = 0.f;
  f32x4 accpv[8] = {};  // wave's 16 rows x 128 cols of h'

  for (int j0 = 0; j0 < NN; j0 += 64) {
    // ---- S = g @ h^T (split precision) ----
    f32x4 accs[2] = {};
#pragma unroll
    for (int kk = 0; kk < 8; ++kk) {
#pragma unroll
      for (int cf = 0; cf < 2; ++cf) {
        int ho = (j0 + wc * 32 + cf * 16 + l15) * DD + kk * 32 + koff;
        bf16x8 bh = *(const bf16x8*)(hHi + ho);
        bf16x8 bl = *(const bf16x8*)(hLo + ho);
        accs[cf] = __builtin_amdgcn_mfma_f32_16x16x32_bf16(ghi[kk], bh, accs[cf], 0, 0, 0);
        accs[cf] = __builtin_amdgcn_mfma_f32_16x16x32_bf16(glo[kk], bh, accs[cf], 0, 0, 0);
        accs[cf] = __builtin_amdgcn_mfma_f32_16x16x32_bf16(ghi[kk], bl, accs[cf], 0, 0, 0);
      }
    }
    // ---- bias + leaky + mask -> LDS ----
#pragma unroll
    for (int cf = 0; cf < 2; ++cf) {
      int lcol = wc * 32 + cf * 16 + l15;
      float axv = ax[j0 + lcol];
#pragma unroll
      for (int r = 0; r < 4; ++r) {
        float v = accs[cf][r] + axv + ay4[r];
        v = (v > 0.f) ? v : 0.2f * v;
        int a = adj[(row0 + srow + r) * NN + j0 + lcol];
        sS[srow + r][lcol] = (a > 0) ? v : -9.0e15f;
      }
    }
    __syncthreads();
    // ---- online softmax (8 lanes/row, shfl_xor reduce) ----
    float p8[8];
    float tmax = -__builtin_inff();
#pragma unroll
    for (int c = 0; c < 8; ++c) {
      p8[c] = sS[smrow][smc0 + c];
      tmax = fmaxf(tmax, p8[c]);
    }
    tmax = fmaxf(tmax, __shfl_xor(tmax, 1));
    tmax = fmaxf(tmax, __shfl_xor(tmax, 2));
    tmax = fmaxf(tmax, __shfl_xor(tmax, 4));
    float m_new = fmaxf(m_run, tmax);
    float scale = __expf(m_run - m_new);
    float psum = 0.f;
    union { short s[8]; bf16x8 v; } pu;
#pragma unroll
    for (int c = 0; c < 8; ++c) {
      float p = __expf(p8[c] - m_new);  // masked (-9e15) -> 0
      psum += p;
      pu.s[c] = f2bf(p);
    }
    *(bf16x8*)(&sP[smrow][smc0]) = pu.v;
    psum += __shfl_xor(psum, 1);
    psum += __shfl_xor(psum, 2);
    psum += __shfl_xor(psum, 4);
    l_run = l_run * scale + psum;
    m_run = m_new;
    if ((tid & 7) == 0) sScale[smrow] = scale;
    __syncthreads();
    // ---- PV: rescale accumulator, then P @ feat ----
    float sc4[4];
#pragma unroll
    for (int r = 0; r < 4; ++r) sc4[r] = sScale[srow + r];
#pragma unroll
    for (int cf = 0; cf < 8; ++cf) {
#pragma unroll
      for (int r = 0; r < 4; ++r) accpv[cf][r] *= sc4[r];
    }
#pragma unroll
    for (int kk = 0; kk < 2; ++kk) {
      bf16x8 pf = *(const bf16x8*)(&sP[wr * 16 + l15][kk * 32 + koff]);
#pragma unroll
      for (int cf = 0; cf < 8; ++cf) {
        bf16x8 bf = *(const bf16x8*)(fT + (wc * 128 + cf * 16 + l15) * NN + j0 + kk * 32 + koff);
        accpv[cf] = __builtin_amdgcn_mfma_f32_16x16x32_bf16(pf, bf, accpv[cf], 0, 0, 0);
      }
    }
    __syncthreads();  // protect sS/sP before next tile overwrites
  }
  if ((tid & 7) == 0) sL[smrow] = l_run;
  __syncthreads();
  float inv4[4];
#pragma unroll
  for (int r = 0; r < 4; ++r) inv4[r] = 1.f / sL[srow + r];
#pragma unroll
  for (int cf = 0; cf < 8; ++cf) {
    int col = wc * 128 + cf * 16 + l15;
#pragma unroll
    for (int r = 0; r < 4; ++r)
      hp[(row0 + srow + r) * DD + col] = f2bf(accpv[cf][r] * inv4[r]);
  }
}

extern "C" void kernel_launch(void* const* d_in, const int* in_sizes, int n_in,
                              void* d_out, int out_size, void* d_ws, size_t ws_size,
                              hipStream_t stream) {
  const float* feat = (const float*)d_in[0];
  const int*   adj  = (const int*)d_in[1];
  const float* W    = (const float*)d_in[2];
  const float* a1   = (const float*)d_in[3];
  const float* a2   = (const float*)d_in[4];
  const float* a12  = (const float*)d_in[5];
  const float* W1   = (const float*)d_in[6];
  const float* W2   = (const float*)d_in[7];
  float* out = (float*)d_out;
  (void)in_sizes; (void)n_in; (void)out_size; (void)ws_size;

  char* ws = (char*)d_ws;
  size_t off = 0;
  auto alloc = [&](size_t b) { void* p = ws + off; off += (b + 255) & ~(size_t)255; return p; };
  short* featHi = (short*)alloc((size_t)NN * DD * 2);
  short* featLo = (short*)alloc((size_t)NN * DD * 2);
  short* fT     = (short*)alloc((size_t)NN * DD * 2);
  short* hHi    = (short*)alloc((size_t)NN * DD * 2);
  short* hLo    = (short*)alloc((size_t)NN * DD * 2);
  short* gHi    = (short*)alloc((size_t)NN * DD * 2);
  short* gLo    = (short*)alloc((size_t)NN * DD * 2);
  short* hp     = (short*)alloc((size_t)NN * DD * 2);
  short* WTh    = (short*)alloc((size_t)DD * DD * 2);
  short* WTl    = (short*)alloc((size_t)DD * DD * 2);
  short* A12Th  = (short*)alloc((size_t)DD * DD * 2);
  short* A12Tl  = (short*)alloc((size_t)DD * DD * 2);
  short* W1T    = (short*)alloc((size_t)DD * DD * 2);
  short* W2T    = (short*)alloc((size_t)DD * DD * 2);
  float* axv    = (float*)alloc((size_t)NN * 4);
  float* ayv    = (float*)alloc((size_t)NN * 4);

  cvt_split_kernel<<<2048, 256, 0, stream>>>(feat, featHi, featLo, NN * DD);
  featT_kernel<<<dim3(NN / 256, DD), 256, 0, stream>>>(feat, fT);
  transpose_split_kernel<<<DD, DD, 0, stream>>>(W, WTh, WTl);
  transpose_split_kernel<<<DD, DD, 0, stream>>>(a12, A12Th, A12Tl);
  transpose_split_kernel<<<DD, DD, 0, stream>>>(W1, W1T, nullptr);
  transpose_split_kernel<<<DD, DD, 0, stream>>>(W2, W2T, nullptr);
  // h = feat @ W  (split precision, hi/lo out)
  gemm_bt64_kernel<<<dim3(NN / 64, DD / 64), 256, 0, stream>>>(
      featHi, featLo, WTh, WTl, nullptr, nullptr, hHi, hLo, nullptr, 0);
  // g = h @ a12  (split precision, hi/lo out)
  gemm_bt64_kernel<<<dim3(NN / 64, DD / 64), 256, 0, stream>>>(
      hHi, hLo, A12Th, A12Tl, nullptr, nullptr, gHi, gLo, nullptr, 0);
  axay_kernel<<<NN / 4, 256, 0, stream>>>(hHi, hLo, a1, a2, axv, ayv);
  attn_kernel<<<NN / 32, 256, 0, stream>>>(gHi, gLo, hHi, hLo, fT, axv, ayv, adj, hp);
  // out = elu(feat@W1 + h'@W2)
  gemm_bt64_kernel<<<dim3(NN / 64, DD / 64), 256, 0, stream>>>(
      featHi, nullptr, W1T, nullptr, hp, W2T, nullptr, nullptr, out, 1);
}